// Round 2
// baseline (86.161 us; speedup 1.0000x reference)
//
#include <hip/hip_runtime.h>

#define MDEPTH 5
#define TPB 256
#define LDS_STRIDE 19   // 18 floats/row + 1 pad -> odd stride, conflict-free-ish

__global__ __launch_bounds__(TPB) void memtap_kernel(
    const float* __restrict__ iq, float* __restrict__ out,
    int B, int S, int T)
{
    const int blocksPerB = (T + TPB - 1) / TPB;
    const int b  = blockIdx.x / blocksPerB;
    const int t0 = (blockIdx.x % blocksPerB) * TPB;
    const int tid = threadIdx.x;

    __shared__ float lds[TPB * LDS_STRIDE];

    const int t = t0 + tid;
    if (t < T) {
        const int n = t + MDEPTH;                        // n in [5, S-1]
        const float2* iqb = (const float2*)iq + (size_t)b * S;

        float2 v[MDEPTH + 1];
        #pragma unroll
        for (int k = 0; k <= MDEPTH; ++k) v[k] = iqb[n - k];   // v[k] = iq(n-k)

        float* o = &lds[tid * LDS_STRIDE];
        // current_iq
        o[0] = v[0].x;
        o[1] = v[0].y;
        // env_memory: env(n-k), k=0..5
        #pragma unroll
        for (int k = 0; k <= MDEPTH; ++k)
            o[2 + k] = sqrtf(v[k].x * v[k].x + v[k].y * v[k].y);
        // iq_memory: iq(n-1-j), j=0..4, interleaved (i,q)
        #pragma unroll
        for (int j = 0; j < MDEPTH; ++j) {
            o[8 + 2 * j] = v[j + 1].x;
            o[9 + 2 * j] = v[j + 1].y;
        }
    }
    __syncthreads();

    // Coalesced write of this block's contiguous output region as float2.
    const int cnt = min(TPB, T - t0);        // valid rows in this block
    const int nf2 = cnt * 9;                 // float2 elements (18 floats/row)
    float2* ob = (float2*)out + ((size_t)b * T + t0) * 9;
    for (int f = tid; f < nf2; f += TPB) {
        const int r = f / 9;                 // row within block
        const int c = 2 * (f % 9);           // even float column, c+1 same row
        ob[f] = make_float2(lds[r * LDS_STRIDE + c], lds[r * LDS_STRIDE + c + 1]);
    }
}

extern "C" void kernel_launch(void* const* d_in, const int* in_sizes, int n_in,
                              void* d_out, int out_size, void* d_ws, size_t ws_size,
                              hipStream_t stream) {
    (void)in_sizes; (void)n_in; (void)d_ws; (void)ws_size; (void)out_size;
    const float* iq = (const float*)d_in[0];
    float* out = (float*)d_out;

    const int B = 64, S = 16384;
    const int T = S - MDEPTH;                 // 16379
    const int blocksPerB = (T + TPB - 1) / TPB;   // 64
    const int grid = B * blocksPerB;              // 4096

    memtap_kernel<<<grid, TPB, 0, stream>>>(iq, out, B, S, T);
}